// Round 11
// baseline (391.305 us; speedup 1.0000x reference)
//
#include <hip/hip_runtime.h>

// HyperLSTMCell on MI355X (gfx950).  B=65536, D=128, H=256, Z=128, E=16.
// All inputs/outputs f32; internal GEMMs bf16 MFMA (16x16x32).
//
// r11 structure: NO LDS, NO BARRIERS. Everything streams through registers:
//   pre  : cast abuf_fr = FRAGMENT-MAJOR bf16 [hhat0|h0|x] (A-operand images) +
//          fragment-major B images + zw->dw fold (dense Wh'/Wx'/Wb') + bias folds.
//   k1   : per wave: stream 8 K-steps, each step = 2 halves of {4 A-frag loads +
//          4 B-frag loads -> 16 MFMA}; halves double-buffer each other (load h
//          of s+1 right after h of s is consumed). Hyper LSTM epilogue.
//   k2   : hyper-first 12 steps (s0-1 d_yh -> dsc ; s2-3 d_yx -> dsc ;
//          s4-9 main gpre ; s9 acc*=dsc ; s10-11 d_yb MFMA C-in), same streaming.
// Rationale (r10 counters): the per-step barrier existed only to guard the shared
// A-tile in LDS; every wave read the whole tile anyway, so L1/L2 provide the
// sharing. Removing LDS+barriers removes the ds_read pipe cost AND the exposed
// B-load->MFMA latency chain; waves free-run, compiler software-pipelines.
//
// d_out (f32): h1 [B,256] | c1 [B,256] | hhat1 [B,128] | chat1 [B,128]

typedef unsigned short u16;
typedef __attribute__((ext_vector_type(8))) short bf16x8;   // 8 bf16 (4 VGPRs)
typedef __attribute__((ext_vector_type(4))) float f32x4;

#define BATCH 65536

__device__ __forceinline__ u16 f2b(float f) {           // f32 -> bf16 bits, RNE
  unsigned u = __float_as_uint(f);
  u += 0x7fffu + ((u >> 16) & 1u);
  return (u16)(u >> 16);
}
__device__ __forceinline__ unsigned pk2(float a, float b) {   // 2xf32 -> packed bf16
  return (unsigned)f2b(a) | ((unsigned)f2b(b) << 16);
}
__device__ __forceinline__ float upk_lo(unsigned u) { return __uint_as_float(u << 16); }
__device__ __forceinline__ float upk_hi(unsigned u) { return __uint_as_float(u & 0xffff0000u); }
__device__ __forceinline__ float sigf(float x) { return 1.0f / (1.0f + __expf(-x)); }
__device__ __forceinline__ float tanhfast(float x) {    // clamped exp-based tanh
  float xc = fminf(fmaxf(x, -15.f), 15.f);
  float e = __expf(2.f * xc);
  return (e - 1.f) / (e + 1.f);
}

// ---------------------------------------------------------------------------
// pre: fragment-major input-cast + weight prep.
// A-frag image layout (u16 idx): (((rb*8 + kc)*4 + mf)*2 + h)*512 + lane*8 + j
//   element = Ain[rb*64 + mf*16 + (lane&15)][kc*64 + h*32 + (lane>>4)*8 + j]
//   where Ain = [hhat0 | h0 | x] (512 cols).  Same lane->element map the old
//   LDS path delivered, so MFMA math is bit-identical to r10.
// B-frag image layout: tile*16384 + ((wc*2+h)*4+g)*512 + lane*8 + j  (as r10).
// ---------------------------------------------------------------------------
__global__ __launch_bounds__(256) void hlstm_pre(
    const float* __restrict__ hhat0, const float* __restrict__ h0,
    const float* __restrict__ x, u16* __restrict__ abuf_fr,
    const float* __restrict__ hweight, const float* __restrict__ hbias,
    const float* __restrict__ zw_h, const float* __restrict__ zw_x, const float* __restrict__ zw_b,
    const float* __restrict__ zb_h, const float* __restrict__ zb_x,
    const float* __restrict__ dw_h, const float* __restrict__ dw_x, const float* __restrict__ dw_b,
    const float* __restrict__ weight, const float* __restrict__ bias,
    u16* __restrict__ hw_fr, float* __restrict__ hbias_r,
    u16* __restrict__ w_fr,  float* __restrict__ bias_r,
    u16* __restrict__ whp_fr, u16* __restrict__ wxp_fr, u16* __restrict__ wbp_fr,
    float* __restrict__ bhp_r, float* __restrict__ bxp_r)
{
  if (blockIdx.x < 4096) {
    // ---- cast part: abuf_fr (fragment-major). 4.19M tasks x 8 bf16.
    const size_t stride = (size_t)4096 * 256;
    for (size_t i = (size_t)blockIdx.x * 256 + threadIdx.x;
         i < (size_t)4194304; i += stride) {
      const int lane = (int)(i & 63);
      const int h    = (int)((i >> 6) & 1);
      const int mf   = (int)((i >> 7) & 3);
      const int kc   = (int)((i >> 9) & 7);
      const int rb   = (int)(i >> 12);
      const int row = rb * 64 + mf * 16 + (lane & 15);
      const int col = kc * 64 + h * 32 + (lane >> 4) * 8;
      const float* src;
      if (col < 128)      src = hhat0 + (size_t)row * 128 + col;
      else if (col < 384) src = h0 + (size_t)row * 256 + (col - 128);
      else                src = x + (size_t)row * 128 + (col - 384);
      float4 v0 = ((const float4*)src)[0];
      float4 v1 = ((const float4*)src)[1];
      alignas(16) u16 o[8] = {f2b(v0.x), f2b(v0.y), f2b(v0.z), f2b(v0.w),
                              f2b(v1.x), f2b(v1.y), f2b(v1.z), f2b(v1.w)};
      *(uint4*)(abuf_fr + i * 8) = *(const uint4*)o;
    }
    return;
  }
  // ---- prep part: fragment-major weight images (unchanged from r10).
  const int tid = (blockIdx.x - 4096) * 256 + threadIdx.x;
  const int nt  = 512 * 256;

  // hw_fr: 16 tiles (hb*8+s), phys col = g*128 + hb*64 + hh
  for (int i = tid; i < 16 * 16384; i += nt) {
    int tile = i >> 14, r = i & 16383;
    int wc = r >> 12, h = (r >> 11) & 1, g = (r >> 9) & 3;
    int lane = (r >> 3) & 63, j = r & 7;
    int hb = tile >> 3, s = tile & 7;
    int k = s * 64 + h * 32 + (lane >> 4) * 8 + j;
    int col = g * 128 + hb * 64 + wc * 16 + (lane & 15);
    hw_fr[i] = f2b(hweight[k * 512 + col]);
  }
  // w_fr: 24 tiles (hb*6+s), phys col = g*256 + hb*64 + hh
  for (int i = tid; i < 24 * 16384; i += nt) {
    int tile = i >> 14, r = i & 16383;
    int wc = r >> 12, h = (r >> 11) & 1, g = (r >> 9) & 3;
    int lane = (r >> 3) & 63, j = r & 7;
    int hb = tile / 6, s = tile % 6;
    int k = s * 64 + h * 32 + (lane >> 4) * 8 + j;
    int col = g * 256 + hb * 64 + wc * 16 + (lane & 15);
    w_fr[i] = f2b(weight[k * 1024 + col]);
  }
  // folded hyper fragments: 3 mats x 8 tiles (hb*2+s); W'[k][(g,h)] = sum_e zw*dw
  for (int i = tid; i < 3 * 8 * 16384; i += nt) {
    int mat = i / (8 * 16384), rem = i % (8 * 16384);
    int tile = rem >> 14, r = rem & 16383;
    int wc = r >> 12, h = (r >> 11) & 1, g = (r >> 9) & 3;
    int lane = (r >> 3) & 63, j = r & 7;
    int hb = tile >> 1, s = tile & 1;
    int k = s * 64 + h * 32 + (lane >> 4) * 8 + j;       // 0..127
    int colh = hb * 64 + wc * 16 + (lane & 15);
    const float* zw = (mat == 0) ? zw_h : (mat == 1) ? zw_x : zw_b;
    const float* dw = (mat == 0) ? dw_h : (mat == 1) ? dw_x : dw_b;
    float sv = 0.f;
#pragma unroll
    for (int e = 0; e < 16; ++e)
      sv += zw[k * 64 + g * 16 + e] * dw[g * 4096 + e * 256 + colh];
    u16* dst = (mat == 0) ? whp_fr : (mat == 1) ? wxp_fr : wbp_fr;
    dst[rem] = f2b(sv);
  }
  // bias folds (virtual order hb*256 + g*64 + hh)
  for (int i = tid; i < 1024; i += nt) {
    int hb = i >> 8, g = (i >> 6) & 3, hh = i & 63;
    int h = hb * 64 + hh;
    float sh = 0.f, sx = 0.f;
#pragma unroll
    for (int e = 0; e < 16; ++e) {
      sh += zb_h[g * 16 + e] * dw_h[g * 4096 + e * 256 + h];
      sx += zb_x[g * 16 + e] * dw_x[g * 4096 + e * 256 + h];
    }
    bhp_r[i] = sh; bxp_r[i] = sx;
    bias_r[i] = bias[g * 256 + h];
  }
  for (int i = tid; i < 512; i += nt) {
    int gate = (i >> 6) & 3, hb = i >> 8, hh = i & 63;
    hbias_r[i] = hbias[gate * 128 + hb * 64 + hh];
  }
}

// ---------------------------------------------------------------------------
// k1: hyper GEMM (K=512, 8 steps) + hyper LSTM. 2048 blocks x 256 threads.
// Pure streaming registers, half-step double-buffering, no LDS/barriers.
// ---------------------------------------------------------------------------
__global__ __launch_bounds__(256, 3) void hlstm_k1(
    const u16* __restrict__ abuf_fr, const float* __restrict__ chat0,
    const u16* __restrict__ hw_fr, const float* __restrict__ hbias_r,
    float* __restrict__ d_out, u16* __restrict__ hbuf)
{
  const int f = blockIdx.x;                 // 0..2047
  const int xcd = f & 7, s2 = f >> 3;
  const int rb = xcd * 128 + (s2 >> 1), hb = s2 & 1;
  const int t = threadIdx.x;
  const int lane = t & 63, wc = t >> 6;
  const int lr = lane & 15, kg = lane >> 4;

  f32x4 acc[4][4];
  const f32x4 zzero = {0.f, 0.f, 0.f, 0.f};
#pragma unroll
  for (int mf = 0; mf < 4; ++mf)
#pragma unroll
    for (int g = 0; g < 4; ++g) acc[mf][g] = zzero;

  bf16x8 A0[4], A1[4], B0[4], B1[4];
  auto loadA = [&](bf16x8 (&Ar)[4], int kc, int h) {
#pragma unroll
    for (int mf = 0; mf < 4; ++mf)
      Ar[mf] = *(const bf16x8*)&abuf_fr[((((size_t)rb * 8 + kc) * 4 + mf) * 2 + h) * 512 + lane * 8];
  };
  auto loadBh = [&](bf16x8 (&Br)[4], const u16* bt, int h) {
#pragma unroll
    for (int g = 0; g < 4; ++g)
      Br[g] = *(const bf16x8*)&bt[((wc * 2 + h) * 4 + g) * 512 + lane * 8];
  };
  auto half = [&](const bf16x8 (&Ar)[4], const bf16x8 (&Br)[4]) {
#pragma unroll
    for (int mf = 0; mf < 4; ++mf)
#pragma unroll
      for (int g = 0; g < 4; ++g)
        acc[mf][g] = __builtin_amdgcn_mfma_f32_16x16x32_bf16(Ar[mf], Br[g], acc[mf][g], 0, 0, 0);
  };

  loadA(A0, 0, 0); loadBh(B0, hw_fr + (size_t)(hb * 8) * 16384, 0);
  loadA(A1, 0, 1); loadBh(B1, hw_fr + (size_t)(hb * 8) * 16384, 1);

#pragma unroll
  for (int ks = 0; ks < 8; ++ks) {
    half(A0, B0);
    if (ks < 7) { loadA(A0, ks + 1, 0); loadBh(B0, hw_fr + (size_t)(hb * 8 + ks + 1) * 16384, 0); }
    half(A1, B1);
    if (ks < 7) { loadA(A1, ks + 1, 1); loadBh(B1, hw_fr + (size_t)(hb * 8 + ks + 1) * 16384, 1); }
  }

  float hb4[4];
#pragma unroll
  for (int g = 0; g < 4; ++g) hb4[g] = hbias_r[hb * 256 + g * 64 + wc * 16 + lr];
  const int zc = hb * 64 + wc * 16 + lr;
  float* out_hh = d_out + (size_t)BATCH * 512;
  float* out_ch = d_out + (size_t)BATCH * 640;
#pragma unroll
  for (int mf = 0; mf < 4; ++mf)
#pragma unroll
    for (int r = 0; r < 4; ++r) {
      const int row = rb * 64 + mf * 16 + kg * 4 + r;
      const float gi = acc[mf][0][r] + hb4[0];
      const float gg = acc[mf][1][r] + hb4[1];
      const float gf = acc[mf][2][r] + hb4[2];
      const float go = acc[mf][3][r] + hb4[3];
      const float c0v = chat0[(size_t)row * 128 + zc];
      const float c1v = sigf(gf) * c0v + sigf(gi) * tanhfast(gg);
      const float h1v = sigf(go) * tanhfast(c1v);
      out_hh[(size_t)row * 128 + zc] = h1v;
      out_ch[(size_t)row * 128 + zc] = c1v;
      hbuf[(size_t)row * 128 + zc] = f2b(h1v);
    }
}

// ---------------------------------------------------------------------------
// k2: hyper-first 12 streaming K-steps, no LDS/barriers. 4096 x 256.
//   s0-1 d_yh -> dsc ; s2-3 d_yx -> dsc ; s4-9 main gpre ; s9 acc*=dsc ;
//   s10-11 d_yb MFMA C-in. A: frags from abuf_fr (main) / hbuf gather (hyper).
// ---------------------------------------------------------------------------
__global__ __launch_bounds__(256, 2) void hlstm_k2(
    const u16* __restrict__ abuf_fr, const u16* __restrict__ hbuf,
    const float* __restrict__ c0,
    const u16* __restrict__ w_fr, const float* __restrict__ bias_r,
    const u16* __restrict__ whp_fr, const u16* __restrict__ wxp_fr, const u16* __restrict__ wbp_fr,
    const float* __restrict__ bhp_r, const float* __restrict__ bxp_r,
    float* __restrict__ d_out)
{
  const int f = blockIdx.x;                 // 0..4095
  const int xcd = f & 7, s4 = f >> 3;
  const int rb = xcd * 128 + (s4 >> 2), hb = s4 & 3;
  const int t = threadIdx.x;
  const int lane = t & 63, wc = t >> 6;
  const int lr = lane & 15, kg = lane >> 4;

  auto bptr = [&](int s) -> const u16* {
    if (s < 2)  return whp_fr + (size_t)(hb * 2 + s) * 16384;
    if (s < 4)  return wxp_fr + (size_t)(hb * 2 + s - 2) * 16384;
    if (s < 10) return w_fr  + (size_t)(hb * 6 + s - 4) * 16384;
    return wbp_fr + (size_t)(hb * 2 + s - 10) * 16384;
  };

  f32x4 acc[4][4];
  const f32x4 zzero = {0.f, 0.f, 0.f, 0.f};
#pragma unroll
  for (int mf = 0; mf < 4; ++mf)
#pragma unroll
    for (int g = 0; g < 4; ++g) acc[mf][g] = zzero;

  unsigned dsc[4][4][2];                    // packed-bf16 running dscale (32 VGPR)

  bf16x8 A0[4], A1[4], B0[4], B1[4];
  // A loader: main steps (4<=s<10) from abuf_fr kc=s-2; hyper steps gather hbuf.
  auto loadA = [&](bf16x8 (&Ar)[4], int s, int h) {
    if (s >= 4 && s < 10) {
      const int kc = s - 2;
#pragma unroll
      for (int mf = 0; mf < 4; ++mf)
        Ar[mf] = *(const bf16x8*)&abuf_fr[((((size_t)rb * 8 + kc) * 4 + mf) * 2 + h) * 512 + lane * 8];
    } else {
      const int c = s & 1;
#pragma unroll
      for (int mf = 0; mf < 4; ++mf)
        Ar[mf] = *(const bf16x8*)&hbuf[(size_t)(rb * 64 + mf * 16 + lr) * 128 + c * 64 + h * 32 + kg * 8];
    }
  };
  auto loadBh = [&](bf16x8 (&Br)[4], const u16* bt, int h) {
#pragma unroll
    for (int g = 0; g < 4; ++g)
      Br[g] = *(const bf16x8*)&bt[((wc * 2 + h) * 4 + g) * 512 + lane * 8];
  };
  auto half = [&](const bf16x8 (&Ar)[4], const bf16x8 (&Br)[4]) {
#pragma unroll
    for (int mf = 0; mf < 4; ++mf)
#pragma unroll
      for (int g = 0; g < 4; ++g)
        acc[mf][g] = __builtin_amdgcn_mfma_f32_16x16x32_bf16(Ar[mf], Br[g], acc[mf][g], 0, 0, 0);
  };

  loadA(A0, 0, 0); loadBh(B0, bptr(0), 0);
  loadA(A1, 0, 1); loadBh(B1, bptr(0), 1);

#pragma unroll
  for (int s = 0; s < 12; ++s) {
    if (s == 2 || s == 4) {                 // new phase: re-zero single acc
#pragma unroll
      for (int mf = 0; mf < 4; ++mf)
#pragma unroll
        for (int g = 0; g < 4; ++g) acc[mf][g] = zzero;
    }
    half(A0, B0);
    if (s < 11) { loadA(A0, s + 1, 0); loadBh(B0, bptr(s + 1), 0); }
    half(A1, B1);
    if (s < 11) { loadA(A1, s + 1, 1); loadBh(B1, bptr(s + 1), 1); }

    if (s == 1) {                           // dsc = pack(d_yh + bh')
      float bh4[4];
#pragma unroll
      for (int g = 0; g < 4; ++g) bh4[g] = bhp_r[hb * 256 + g * 64 + wc * 16 + lr];
#pragma unroll
      for (int mf = 0; mf < 4; ++mf)
#pragma unroll
        for (int g = 0; g < 4; ++g) {
          dsc[mf][g][0] = pk2(acc[mf][g][0] + bh4[g], acc[mf][g][1] + bh4[g]);
          dsc[mf][g][1] = pk2(acc[mf][g][2] + bh4[g], acc[mf][g][3] + bh4[g]);
        }
    } else if (s == 3) {                    // dsc *= (d_yx + bx')
      float bx4[4];
#pragma unroll
      for (int g = 0; g < 4; ++g) bx4[g] = bxp_r[hb * 256 + g * 64 + wc * 16 + lr];
#pragma unroll
      for (int mf = 0; mf < 4; ++mf)
#pragma unroll
        for (int g = 0; g < 4; ++g) {
          float d0 = upk_lo(dsc[mf][g][0]) * (acc[mf][g][0] + bx4[g]);
          float d1 = upk_hi(dsc[mf][g][0]) * (acc[mf][g][1] + bx4[g]);
          float d2 = upk_lo(dsc[mf][g][1]) * (acc[mf][g][2] + bx4[g]);
          float d3 = upk_hi(dsc[mf][g][1]) * (acc[mf][g][3] + bx4[g]);
          dsc[mf][g][0] = pk2(d0, d1);
          dsc[mf][g][1] = pk2(d2, d3);
        }
    } else if (s == 9) {                    // acc(gpre) *= dscale
#pragma unroll
      for (int mf = 0; mf < 4; ++mf)
#pragma unroll
        for (int g = 0; g < 4; ++g) {
          acc[mf][g][0] *= upk_lo(dsc[mf][g][0]);
          acc[mf][g][1] *= upk_hi(dsc[mf][g][0]);
          acc[mf][g][2] *= upk_lo(dsc[mf][g][1]);
          acc[mf][g][3] *= upk_hi(dsc[mf][g][1]);
        }
    }
  }

  // ---- epilogue: main LSTM cell (acc = gpre*dscale + d_yb)
  const int hcol = hb * 64 + wc * 16 + lr;
  float b4[4];
#pragma unroll
  for (int g = 0; g < 4; ++g) b4[g] = bias_r[hb * 256 + g * 64 + wc * 16 + lr];
  float* out_c1 = d_out + (size_t)BATCH * 256;
#pragma unroll
  for (int mf = 0; mf < 4; ++mf)
#pragma unroll
    for (int r = 0; r < 4; ++r) {
      const int row = rb * 64 + mf * 16 + kg * 4 + r;
      const float gi = acc[mf][0][r] + b4[0];
      const float gg = acc[mf][1][r] + b4[1];
      const float gf = acc[mf][2][r] + b4[2];
      const float go = acc[mf][3][r] + b4[3];
      const float c0v = c0[(size_t)row * 256 + hcol];
      const float c1v = sigf(gf) * c0v + sigf(gi) * tanhfast(gg);
      const float h1v = sigf(go) * tanhfast(c1v);
      d_out[(size_t)row * 256 + hcol]  = h1v;
      out_c1[(size_t)row * 256 + hcol] = c1v;
    }
}

// ---------------------------------------------------------------------------
extern "C" void kernel_launch(void* const* d_in, const int* in_sizes, int n_in,
                              void* d_out, int out_size, void* d_ws, size_t ws_size,
                              hipStream_t stream)
{
  (void)in_sizes; (void)n_in; (void)out_size; (void)ws_size;
  const float* x       = (const float*)d_in[0];
  const float* h0      = (const float*)d_in[1];
  const float* c0      = (const float*)d_in[2];
  const float* hhat0   = (const float*)d_in[3];
  const float* chat0   = (const float*)d_in[4];
  const float* hweight = (const float*)d_in[5];
  const float* hbias   = (const float*)d_in[6];
  const float* zw_h    = (const float*)d_in[7];
  const float* zw_x    = (const float*)d_in[8];
  const float* zw_b    = (const float*)d_in[9];
  const float* zb_h    = (const float*)d_in[10];
  const float* zb_x    = (const float*)d_in[11];
  const float* dw_h    = (const float*)d_in[12];
  const float* dw_x    = (const float*)d_in[13];
  const float* dw_b    = (const float*)d_in[14];
  const float* weight  = (const float*)d_in[15];
  const float* bias    = (const float*)d_in[16];

  // workspace layout (bytes, 16B-aligned); total ~86 MB
  char* wsb = (char*)d_ws;
  u16*   abuf_fr = (u16*)(wsb + 0);              // B*512*2   = 67108864
  u16*   hbuf    = (u16*)(wsb + 67108864);       // B*128*2   = 16777216
  u16*   hw_fr   = (u16*)(wsb + 83886080);       // 16*16384*2 = 524288
  u16*   w_fr    = (u16*)(wsb + 84410368);       // 24*16384*2 = 786432
  u16*   whp_fr  = (u16*)(wsb + 85196800);       // 8*16384*2  = 262144
  u16*   wxp_fr  = (u16*)(wsb + 85458944);
  u16*   wbp_fr  = (u16*)(wsb + 85721088);
  float* hbias_r = (float*)(wsb + 85983232);     // 512*4
  float* bias_r  = (float*)(wsb + 85985280);     // 1024*4
  float* bhp_r   = (float*)(wsb + 85989376);     // 1024*4
  float* bxp_r   = (float*)(wsb + 85993472);     // 1024*4

  hlstm_pre<<<dim3(4608), dim3(256), 0, stream>>>(
      hhat0, h0, x, abuf_fr,
      hweight, hbias, zw_h, zw_x, zw_b, zb_h, zb_x, dw_h, dw_x, dw_b, weight, bias,
      hw_fr, hbias_r, w_fr, bias_r, whp_fr, wxp_fr, wbp_fr, bhp_r, bxp_r);

  hlstm_k1<<<dim3(2048), dim3(256), 0, stream>>>(
      abuf_fr, chat0, hw_fr, hbias_r, (float*)d_out, hbuf);

  hlstm_k2<<<dim3(4096), dim3(256), 0, stream>>>(
      abuf_fr, hbuf, c0, w_fr, bias_r, whp_fr, wxp_fr, wbp_fr, bhp_r, bxp_r, (float*)d_out);
}

// Round 12
// 294.813 us; speedup vs baseline: 1.3273x; 1.3273x over previous
//
#include <hip/hip_runtime.h>

// HyperLSTMCell on MI355X (gfx950).  B=65536, D=128, H=256, Z=128, E=16.
// All inputs/outputs f32; internal GEMMs bf16 MFMA (16x16x32).
//
// r12 structure: WAVE-AUTONOMOUS STREAMING. 64-thread (1-wave) blocks, ZERO
// barriers. Each wave: private ring-2 A-tile in LDS (16 KB, staged via
// global_load_lds with the proven m173 swizzle image), B in registers
// (fragment-major images), sync via own-wave counted vmcnt only:
//   step s: s_waitcnt vmcnt(8)   <- forces stage(s) (issued top of s-1; 1-step cover)
//           stage(s+1) -> ring buf (s+1)&1 (opposite buffer: safe at distance 1)
//           sweep(s): ds_read A + 32 MFMA (compiler's counted vmcnt covers B(s))
//           loadB(s+1)
// Register law (r8-r11 evidence): __launch_bounds__(N,2) caps UNIFIED regs at
// 192/wave. k2 demand ~174 (acc64+dsc32+breg32+afr16+addr), k1 ~140 -> fit.
// Grid carries (rb, hb, wc); XCD swizzle groups same-rb siblings per XCD.
//
// d_out (f32): h1 [B,256] | c1 [B,256] | hhat1 [B,128] | chat1 [B,128]

typedef unsigned short u16;
typedef __attribute__((ext_vector_type(8))) short bf16x8;   // 8 bf16 (4 VGPRs)
typedef __attribute__((ext_vector_type(4))) float f32x4;

#define BATCH 65536

__device__ __forceinline__ u16 f2b(float f) {           // f32 -> bf16 bits, RNE
  unsigned u = __float_as_uint(f);
  u += 0x7fffu + ((u >> 16) & 1u);
  return (u16)(u >> 16);
}
__device__ __forceinline__ unsigned pk2(float a, float b) {   // 2xf32 -> packed bf16
  return (unsigned)f2b(a) | ((unsigned)f2b(b) << 16);
}
__device__ __forceinline__ float upk_lo(unsigned u) { return __uint_as_float(u << 16); }
__device__ __forceinline__ float upk_hi(unsigned u) { return __uint_as_float(u & 0xffff0000u); }
__device__ __forceinline__ float sigf(float x) { return 1.0f / (1.0f + __expf(-x)); }
__device__ __forceinline__ float tanhfast(float x) {    // clamped exp-based tanh
  float xc = fminf(fmaxf(x, -15.f), 15.f);
  float e = __expf(2.f * xc);
  return (e - 1.f) / (e + 1.f);
}
// LDS XOR swizzle for [row][64] bf16 A-tiles (G4).
__device__ __forceinline__ int swz(int r, int c) { return r * 64 + (c ^ ((r & 7) << 3)); }

// wave-local A-stage fence: force the stage issued one step ago (8 newest
// VMEM ops may remain in flight = this step's B loads OR next stage).
#define WAVE_FENCE8() do { \
  asm volatile("s_waitcnt vmcnt(8)" ::: "memory"); \
  __builtin_amdgcn_sched_barrier(0); } while (0)

// async global->LDS, 16B per lane (m97: global_load_lds_dwordx4)
__device__ __forceinline__ void gl_lds16(const u16* g, u16* l) {
  __builtin_amdgcn_global_load_lds(
      (const __attribute__((address_space(1))) void*)g,
      (__attribute__((address_space(3))) void*)l, 16, 0, 0);
}
// 1-wave stage of a 64x64 A-tile (8 KB) from row-major bf16 (stride ldk) into
// the swizzled LDS image: linear LDS dest + XOR-permuted GLOBAL source (m173).
// 8 gl_lds instructions, 1 KB each.
__device__ __forceinline__ void stageA1(const u16* base, int ldk, u16* dst, int lane) {
  const int rsub = lane >> 3;                        // row-within-8-group
  const int qs = ((lane & 7) ^ rsub) << 3;           // (r&7) == rsub for all chunks
#pragma unroll
  for (int c = 0; c < 8; ++c)
    gl_lds16(base + (size_t)(c * 8 + rsub) * ldk + qs, dst + c * 512);
}

// ---------------------------------------------------------------------------
// pre: fused input-cast + weight prep (fragment-major B).  [r10, unchanged]
// ---------------------------------------------------------------------------
__global__ __launch_bounds__(256) void hlstm_pre(
    const float* __restrict__ hhat0, const float* __restrict__ h0,
    const float* __restrict__ x, u16* __restrict__ abuf,
    const float* __restrict__ hweight, const float* __restrict__ hbias,
    const float* __restrict__ zw_h, const float* __restrict__ zw_x, const float* __restrict__ zw_b,
    const float* __restrict__ zb_h, const float* __restrict__ zb_x,
    const float* __restrict__ dw_h, const float* __restrict__ dw_x, const float* __restrict__ dw_b,
    const float* __restrict__ weight, const float* __restrict__ bias,
    u16* __restrict__ hw_fr, float* __restrict__ hbias_r,
    u16* __restrict__ w_fr,  float* __restrict__ bias_r,
    u16* __restrict__ whp_fr, u16* __restrict__ wxp_fr, u16* __restrict__ wbp_fr,
    float* __restrict__ bhp_r, float* __restrict__ bxp_r)
{
  if (blockIdx.x < 4096) {
    // ---- cast part: abuf[B][512] = bf16([hhat0 | h0 | x])
    const size_t stride = (size_t)4096 * 256;
    for (size_t i = (size_t)blockIdx.x * 256 + threadIdx.x;
         i < (size_t)BATCH * 64; i += stride) {
      const size_t b = i >> 6; const int c = (int)(i & 63);
      const float* src;
      if (c < 16)      src = hhat0 + b * 128 + c * 8;
      else if (c < 48) src = h0 + b * 256 + (size_t)(c - 16) * 8;
      else             src = x + b * 128 + (size_t)(c - 48) * 8;
      float4 v0 = ((const float4*)src)[0];
      float4 v1 = ((const float4*)src)[1];
      alignas(16) u16 o[8] = {f2b(v0.x), f2b(v0.y), f2b(v0.z), f2b(v0.w),
                              f2b(v1.x), f2b(v1.y), f2b(v1.z), f2b(v1.w)};
      *(uint4*)(abuf + i * 8) = *(const uint4*)o;
    }
    return;
  }
  // ---- prep part: fragment-major images.
  // frag index: i = tile*16384 + wc*4096 + h*2048 + g*512 + lane*8 + j
  // element    = W_virtual[k = s*64 + h*32 + (lane>>4)*8 + j][n = g*64 + wc*16 + (lane&15)]
  const int tid = (blockIdx.x - 4096) * 256 + threadIdx.x;
  const int nt  = 512 * 256;

  // hw_fr: 16 tiles (hb*8+s), phys col = g*128 + hb*64 + hh
  for (int i = tid; i < 16 * 16384; i += nt) {
    int tile = i >> 14, r = i & 16383;
    int wc = r >> 12, h = (r >> 11) & 1, g = (r >> 9) & 3;
    int lane = (r >> 3) & 63, j = r & 7;
    int hb = tile >> 3, s = tile & 7;
    int k = s * 64 + h * 32 + (lane >> 4) * 8 + j;
    int col = g * 128 + hb * 64 + wc * 16 + (lane & 15);
    hw_fr[i] = f2b(hweight[k * 512 + col]);
  }
  // w_fr: 24 tiles (hb*6+s), phys col = g*256 + hb*64 + hh
  for (int i = tid; i < 24 * 16384; i += nt) {
    int tile = i >> 14, r = i & 16383;
    int wc = r >> 12, h = (r >> 11) & 1, g = (r >> 9) & 3;
    int lane = (r >> 3) & 63, j = r & 7;
    int hb = tile / 6, s = tile % 6;
    int k = s * 64 + h * 32 + (lane >> 4) * 8 + j;
    int col = g * 256 + hb * 64 + wc * 16 + (lane & 15);
    w_fr[i] = f2b(weight[k * 1024 + col]);
  }
  // folded hyper fragments: 3 mats x 8 tiles (hb*2+s); W'[k][(g,h)] = sum_e zw*dw
  for (int i = tid; i < 3 * 8 * 16384; i += nt) {
    int mat = i / (8 * 16384), rem = i % (8 * 16384);
    int tile = rem >> 14, r = rem & 16383;
    int wc = r >> 12, h = (r >> 11) & 1, g = (r >> 9) & 3;
    int lane = (r >> 3) & 63, j = r & 7;
    int hb = tile >> 1, s = tile & 1;
    int k = s * 64 + h * 32 + (lane >> 4) * 8 + j;       // 0..127
    int colh = hb * 64 + wc * 16 + (lane & 15);
    const float* zw = (mat == 0) ? zw_h : (mat == 1) ? zw_x : zw_b;
    const float* dw = (mat == 0) ? dw_h : (mat == 1) ? dw_x : dw_b;
    float sv = 0.f;
#pragma unroll
    for (int e = 0; e < 16; ++e)
      sv += zw[k * 64 + g * 16 + e] * dw[g * 4096 + e * 256 + colh];
    u16* dst = (mat == 0) ? whp_fr : (mat == 1) ? wxp_fr : wbp_fr;
    dst[rem] = f2b(sv);
  }
  // bias folds (virtual order hb*256 + g*64 + hh)
  for (int i = tid; i < 1024; i += nt) {
    int hb = i >> 8, g = (i >> 6) & 3, hh = i & 63;
    int h = hb * 64 + hh;
    float sh = 0.f, sx = 0.f;
#pragma unroll
    for (int e = 0; e < 16; ++e) {
      sh += zb_h[g * 16 + e] * dw_h[g * 4096 + e * 256 + h];
      sx += zb_x[g * 16 + e] * dw_x[g * 4096 + e * 256 + h];
    }
    bhp_r[i] = sh; bxp_r[i] = sx;
    bias_r[i] = bias[g * 256 + h];
  }
  for (int i = tid; i < 512; i += nt) {
    int gate = (i >> 6) & 3, hb = i >> 8, hh = i & 63;
    hbias_r[i] = hbias[gate * 128 + hb * 64 + hh];
  }
}

// ---------------------------------------------------------------------------
// k1: hyper GEMM (K=512, 8 steps) + hyper LSTM. 8192 blocks x 64 threads.
// 1-wave block, ring-2 private A, reg B, no barriers.
// ---------------------------------------------------------------------------
__global__ __launch_bounds__(64, 2) void hlstm_k1(
    const u16* __restrict__ abuf, const float* __restrict__ chat0,
    const u16* __restrict__ hw_fr, const float* __restrict__ hbias_r,
    float* __restrict__ d_out, u16* __restrict__ hbuf)
{
  __shared__ alignas(16) u16 lA[2][64 * 64];
  const int f = blockIdx.x;                 // 0..8191
  const int xcd = f & 7, u = f >> 3;        // u: 0..1023
  const int rb = xcd * 128 + (u >> 3);
  const int sub = u & 7, hb = sub >> 2, wc = sub & 3;
  const int lane = threadIdx.x;             // 0..63
  const int lr = lane & 15, kg = lane >> 4;

  f32x4 acc[4][4];
  const f32x4 zzero = {0.f, 0.f, 0.f, 0.f};
#pragma unroll
  for (int mf = 0; mf < 4; ++mf)
#pragma unroll
    for (int g = 0; g < 4; ++g) acc[mf][g] = zzero;

  const u16* arow = abuf + (size_t)rb * 64 * 512;

  bf16x8 breg[8];
  auto loadB = [&](const u16* bt) {
#pragma unroll
    for (int h = 0; h < 2; ++h)
#pragma unroll
      for (int g = 0; g < 4; ++g)
        breg[h * 4 + g] = *(const bf16x8*)&bt[((wc * 2 + h) * 4 + g) * 512 + lane * 8];
  };
  auto sweep = [&](const u16* cA) {
    __builtin_amdgcn_s_setprio(1);
#pragma unroll
    for (int h = 0; h < 2; ++h)
#pragma unroll
      for (int mf = 0; mf < 4; ++mf) {
        bf16x8 afr = *(const bf16x8*)&cA[swz(mf * 16 + lr, h * 32 + kg * 8)];
#pragma unroll
        for (int g = 0; g < 4; ++g)
          acc[mf][g] = __builtin_amdgcn_mfma_f32_16x16x32_bf16(afr, breg[h * 4 + g], acc[mf][g], 0, 0, 0);
      }
    __builtin_amdgcn_s_setprio(0);
  };

  // prologue: stage A(0), load B(0)
  stageA1(arow, 512, lA[0], lane);
  loadB(hw_fr + (size_t)(hb * 8) * 16384);

#pragma unroll
  for (int ks = 0; ks < 8; ++ks) {
    WAVE_FENCE8();                          // forces stage(ks); <=8 newest ride
    if (ks < 7) stageA1(arow + (ks + 1) * 64, 512, lA[(ks + 1) & 1], lane);
    sweep(lA[ks & 1]);                      // compiler-counted vmcnt covers B(ks)
    if (ks < 7) loadB(hw_fr + (size_t)(hb * 8 + ks + 1) * 16384);
  }

  float hb4[4];
#pragma unroll
  for (int g = 0; g < 4; ++g) hb4[g] = hbias_r[hb * 256 + g * 64 + wc * 16 + lr];
  const int zc = hb * 64 + wc * 16 + lr;
  float* out_hh = d_out + (size_t)BATCH * 512;
  float* out_ch = d_out + (size_t)BATCH * 640;
#pragma unroll
  for (int mf = 0; mf < 4; ++mf)
#pragma unroll
    for (int r = 0; r < 4; ++r) {
      const int row = rb * 64 + mf * 16 + kg * 4 + r;
      const float gi = acc[mf][0][r] + hb4[0];
      const float gg = acc[mf][1][r] + hb4[1];
      const float gf = acc[mf][2][r] + hb4[2];
      const float go = acc[mf][3][r] + hb4[3];
      const float c0v = chat0[(size_t)row * 128 + zc];
      const float c1v = sigf(gf) * c0v + sigf(gi) * tanhfast(gg);
      const float h1v = sigf(go) * tanhfast(c1v);
      out_hh[(size_t)row * 128 + zc] = h1v;
      out_ch[(size_t)row * 128 + zc] = c1v;
      hbuf[(size_t)row * 128 + zc] = f2b(h1v);
    }
}

// ---------------------------------------------------------------------------
// k2: hyper-first 12 K-steps (s0-1 d_yh -> dsc ; s2-3 d_yx -> dsc ; s4-9 main
// gpre ; s9 acc*=dsc ; s10-11 d_yb MFMA C-in). 16384 blocks x 64 threads.
// 1-wave block, ring-2 private A, reg B, no barriers.
// ---------------------------------------------------------------------------
__global__ __launch_bounds__(64, 2) void hlstm_k2(
    const u16* __restrict__ abuf, const u16* __restrict__ hbuf,
    const float* __restrict__ c0,
    const u16* __restrict__ w_fr, const float* __restrict__ bias_r,
    const u16* __restrict__ whp_fr, const u16* __restrict__ wxp_fr, const u16* __restrict__ wbp_fr,
    const float* __restrict__ bhp_r, const float* __restrict__ bxp_r,
    float* __restrict__ d_out)
{
  __shared__ alignas(16) u16 lA[2][64 * 64];
  const int f = blockIdx.x;                 // 0..16383
  const int xcd = f & 7, u = f >> 3;        // u: 0..2047
  const int rb = xcd * 128 + (u >> 4);
  const int sub = u & 15, hb = sub >> 2, wc = sub & 3;
  const int lane = threadIdx.x;             // 0..63
  const int lr = lane & 15, kg = lane >> 4;

  const u16* amain = abuf + (size_t)rb * 64 * 512 + 128;   // [h0|x] cols, ld 512
  const u16* ahyp  = hbuf + (size_t)rb * 64 * 128;         // ld 128

  // steps: 0..3 hyper (Wh',Wx'), 4..9 main, 10..11 hyper (Wb')
  auto aptr = [&](int s) -> const u16* {
    if (s >= 4 && s < 10) return amain + (s - 4) * 64;
    return ahyp + (s & 1) * 64;
  };
  auto aldk = [&](int s) -> int { return (s >= 4 && s < 10) ? 512 : 128; };
  auto bptr = [&](int s) -> const u16* {
    if (s < 2)  return whp_fr + (size_t)(hb * 2 + s) * 16384;
    if (s < 4)  return wxp_fr + (size_t)(hb * 2 + s - 2) * 16384;
    if (s < 10) return w_fr  + (size_t)(hb * 6 + s - 4) * 16384;
    return wbp_fr + (size_t)(hb * 2 + s - 10) * 16384;
  };

  f32x4 acc[4][4];
  const f32x4 zzero = {0.f, 0.f, 0.f, 0.f};
#pragma unroll
  for (int mf = 0; mf < 4; ++mf)
#pragma unroll
    for (int g = 0; g < 4; ++g) acc[mf][g] = zzero;

  unsigned dsc[4][4][2];                    // packed-bf16 running dscale (32 VGPR)

  bf16x8 breg[8];
  auto loadB = [&](const u16* bt) {
#pragma unroll
    for (int h = 0; h < 2; ++h)
#pragma unroll
      for (int g = 0; g < 4; ++g)
        breg[h * 4 + g] = *(const bf16x8*)&bt[((wc * 2 + h) * 4 + g) * 512 + lane * 8];
  };
  auto sweep = [&](const u16* cA) {
    __builtin_amdgcn_s_setprio(1);
#pragma unroll
    for (int h = 0; h < 2; ++h)
#pragma unroll
      for (int mf = 0; mf < 4; ++mf) {
        bf16x8 afr = *(const bf16x8*)&cA[swz(mf * 16 + lr, h * 32 + kg * 8)];
#pragma unroll
        for (int g = 0; g < 4; ++g)
          acc[mf][g] = __builtin_amdgcn_mfma_f32_16x16x32_bf16(afr, breg[h * 4 + g], acc[mf][g], 0, 0, 0);
      }
    __builtin_amdgcn_s_setprio(0);
  };

  // prologue: stage A(0), load B(0)
  stageA1(aptr(0), aldk(0), lA[0], lane);
  loadB(bptr(0));

#pragma unroll
  for (int s = 0; s < 12; ++s) {
    WAVE_FENCE8();                          // forces stage(s); <=8 newest ride
    if (s == 2 || s == 4) {                 // new phase: re-zero single acc
#pragma unroll
      for (int mf = 0; mf < 4; ++mf)
#pragma unroll
        for (int g = 0; g < 4; ++g) acc[mf][g] = zzero;
    }
    if (s < 11) stageA1(aptr(s + 1), aldk(s + 1), lA[(s + 1) & 1], lane);
    sweep(lA[s & 1]);                       // compiler-counted vmcnt covers B(s)
    if (s < 11) loadB(bptr(s + 1));

    if (s == 1) {                           // dsc = pack(d_yh + bh')
      float bh4[4];
#pragma unroll
      for (int g = 0; g < 4; ++g) bh4[g] = bhp_r[hb * 256 + g * 64 + wc * 16 + lr];
#pragma unroll
      for (int mf = 0; mf < 4; ++mf)
#pragma unroll
        for (int g = 0; g < 4; ++g) {
          dsc[mf][g][0] = pk2(acc[mf][g][0] + bh4[g], acc[mf][g][1] + bh4[g]);
          dsc[mf][g][1] = pk2(acc[mf][g][2] + bh4[g], acc[mf][g][3] + bh4[g]);
        }
    } else if (s == 3) {                    // dsc *= (d_yx + bx')
      float bx4[4];
#pragma unroll
      for (int g = 0; g < 4; ++g) bx4[g] = bxp_r[hb * 256 + g * 64 + wc * 16 + lr];
#pragma unroll
      for (int mf = 0; mf < 4; ++mf)
#pragma unroll
        for (int g = 0; g < 4; ++g) {
          float d0 = upk_lo(dsc[mf][g][0]) * (acc[mf][g][0] + bx4[g]);
          float d1 = upk_hi(dsc[mf][g][0]) * (acc[mf][g][1] + bx4[g]);
          float d2 = upk_lo(dsc[mf][g][1]) * (acc[mf][g][2] + bx4[g]);
          float d3 = upk_hi(dsc[mf][g][1]) * (acc[mf][g][3] + bx4[g]);
          dsc[mf][g][0] = pk2(d0, d1);
          dsc[mf][g][1] = pk2(d2, d3);
        }
    } else if (s == 9) {                    // acc(gpre) *= dscale
#pragma unroll
      for (int mf = 0; mf < 4; ++mf)
#pragma unroll
        for (int g = 0; g < 4; ++g) {
          acc[mf][g][0] *= upk_lo(dsc[mf][g][0]);
          acc[mf][g][1] *= upk_hi(dsc[mf][g][0]);
          acc[mf][g][2] *= upk_lo(dsc[mf][g][1]);
          acc[mf][g][3] *= upk_hi(dsc[mf][g][1]);
        }
    }
  }

  // ---- epilogue: main LSTM cell (acc = gpre*dscale + d_yb)
  const int hcol = hb * 64 + wc * 16 + lr;
  float b4[4];
#pragma unroll
  for (int g = 0; g < 4; ++g) b4[g] = bias_r[hb * 256 + g * 64 + wc * 16 + lr];
  float* out_c1 = d_out + (size_t)BATCH * 256;
#pragma unroll
  for (int mf = 0; mf < 4; ++mf)
#pragma unroll
    for (int r = 0; r < 4; ++r) {
      const int row = rb * 64 + mf * 16 + kg * 4 + r;
      const float gi = acc[mf][0][r] + b4[0];
      const float gg = acc[mf][1][r] + b4[1];
      const float gf = acc[mf][2][r] + b4[2];
      const float go = acc[mf][3][r] + b4[3];
      const float c0v = c0[(size_t)row * 256 + hcol];
      const float c1v = sigf(gf) * c0v + sigf(gi) * tanhfast(gg);
      const float h1v = sigf(go) * tanhfast(c1v);
      d_out[(size_t)row * 256 + hcol]  = h1v;
      out_c1[(size_t)row * 256 + hcol] = c1v;
    }
}

// ---------------------------------------------------------------------------
extern "C" void kernel_launch(void* const* d_in, const int* in_sizes, int n_in,
                              void* d_out, int out_size, void* d_ws, size_t ws_size,
                              hipStream_t stream)
{
  (void)in_sizes; (void)n_in; (void)out_size; (void)ws_size;
  const float* x       = (const float*)d_in[0];
  const float* h0      = (const float*)d_in[1];
  const float* c0      = (const float*)d_in[2];
  const float* hhat0   = (const float*)d_in[3];
  const float* chat0   = (const float*)d_in[4];
  const float* hweight = (const float*)d_in[5];
  const float* hbias   = (const float*)d_in[6];
  const float* zw_h    = (const float*)d_in[7];
  const float* zw_x    = (const float*)d_in[8];
  const float* zw_b    = (const float*)d_in[9];
  const float* zb_h    = (const float*)d_in[10];
  const float* zb_x    = (const float*)d_in[11];
  const float* dw_h    = (const float*)d_in[12];
  const float* dw_x    = (const float*)d_in[13];
  const float* dw_b    = (const float*)d_in[14];
  const float* weight  = (const float*)d_in[15];
  const float* bias    = (const float*)d_in[16];

  // workspace layout (bytes, 16B-aligned); total ~86 MB
  char* wsb = (char*)d_ws;
  u16*   abuf    = (u16*)(wsb + 0);              // B*512*2   = 67108864
  u16*   hbuf    = (u16*)(wsb + 67108864);       // B*128*2   = 16777216
  u16*   hw_fr   = (u16*)(wsb + 83886080);       // 16*16384*2 = 524288
  u16*   w_fr    = (u16*)(wsb + 84410368);       // 24*16384*2 = 786432
  u16*   whp_fr  = (u16*)(wsb + 85196800);       // 8*16384*2  = 262144
  u16*   wxp_fr  = (u16*)(wsb + 85458944);
  u16*   wbp_fr  = (u16*)(wsb + 85721088);
  float* hbias_r = (float*)(wsb + 85983232);     // 512*4
  float* bias_r  = (float*)(wsb + 85985280);     // 1024*4
  float* bhp_r   = (float*)(wsb + 85989376);     // 1024*4
  float* bxp_r   = (float*)(wsb + 85993472);     // 1024*4

  hlstm_pre<<<dim3(4608), dim3(256), 0, stream>>>(
      hhat0, h0, x, abuf,
      hweight, hbias, zw_h, zw_x, zw_b, zb_h, zb_x, dw_h, dw_x, dw_b, weight, bias,
      hw_fr, hbias_r, w_fr, bias_r, whp_fr, wxp_fr, wbp_fr, bhp_r, bxp_r);

  hlstm_k1<<<dim3(8192), dim3(64), 0, stream>>>(
      abuf, chat0, hw_fr, hbias_r, (float*)d_out, hbuf);

  hlstm_k2<<<dim3(16384), dim3(64), 0, stream>>>(
      abuf, hbuf, c0, w_fr, bias_r, whp_fr, wxp_fr, wbp_fr, bhp_r, bxp_r, (float*)d_out);
}

// Round 13
// 278.535 us; speedup vs baseline: 1.4049x; 1.0584x over previous
//
#include <hip/hip_runtime.h>

// HyperLSTMCell on MI355X (gfx950).  B=65536, D=128, H=256, Z=128, E=16.
// All inputs/outputs f32; internal GEMMs bf16 MFMA (16x16x32).
//
// r13 structure: 128x128 block tiles (4 waves = 2M x 2N, per-wave 64x64), BOTH
// A and B staged through LDS (16 KB each per K-step, double-buffered = 64 KB ->
// 2 blocks/CU) to halve L2 traffic (r12 analysis: 64x64 tiles => ~3.1 GB L2 for
// k2 ~ 90 us at L2 ceiling; 128x128 => ~1.6 GB). Proven 2-phase ledger (r7):
//   stage(0); wait0_bar;
//   for s: { stage(s+1)->buf^1; sweep(buf); wait0_bar; }
// stage(s+1) overwrites buf[(s-1)&1] whose reads finished before the previous
// barrier; vmcnt(0) drain covered by the sibling block (m114).
// B images: 16 KB tiles [hb][hh32][s], inner [wn][h][g][lane*8] (ds_read = linear,
// conflict-free). A: proven m173 swizzle image, 128 rows via 2x stageA.
//
// d_out (f32): h1 [B,256] | c1 [B,256] | hhat1 [B,128] | chat1 [B,128]

typedef unsigned short u16;
typedef __attribute__((ext_vector_type(8))) short bf16x8;   // 8 bf16 (4 VGPRs)
typedef __attribute__((ext_vector_type(4))) float f32x4;

#define BATCH 65536

__device__ __forceinline__ u16 f2b(float f) {           // f32 -> bf16 bits, RNE
  unsigned u = __float_as_uint(f);
  u += 0x7fffu + ((u >> 16) & 1u);
  return (u16)(u >> 16);
}
__device__ __forceinline__ unsigned pk2(float a, float b) {   // 2xf32 -> packed bf16
  return (unsigned)f2b(a) | ((unsigned)f2b(b) << 16);
}
__device__ __forceinline__ float upk_lo(unsigned u) { return __uint_as_float(u << 16); }
__device__ __forceinline__ float upk_hi(unsigned u) { return __uint_as_float(u & 0xffff0000u); }
__device__ __forceinline__ float sigf(float x) { return 1.0f / (1.0f + __expf(-x)); }
__device__ __forceinline__ float tanhfast(float x) {    // clamped exp-based tanh
  float xc = fminf(fmaxf(x, -15.f), 15.f);
  float e = __expf(2.f * xc);
  return (e - 1.f) / (e + 1.f);
}
// LDS XOR swizzle for [row][64] bf16 A-tiles (G4).
__device__ __forceinline__ int swz(int r, int c) { return r * 64 + (c ^ ((r & 7) << 3)); }

// 2-phase step barrier: drain stage loads, raw barrier, scheduler fence.
__device__ __forceinline__ void wait0_bar() {
  asm volatile("s_waitcnt vmcnt(0)" ::: "memory");
  __builtin_amdgcn_s_barrier();
  __builtin_amdgcn_sched_barrier(0);
}

// async global->LDS, 16B per lane (m97: global_load_lds_dwordx4)
__device__ __forceinline__ void gl_lds16(const u16* g, u16* l) {
  __builtin_amdgcn_global_load_lds(
      (const __attribute__((address_space(1))) void*)g,
      (__attribute__((address_space(3))) void*)l, 16, 0, 0);
}
// stage 64x64 A-subtile (8 KB) from row-major bf16 (stride ldk) into the swizzled
// LDS image: linear LDS dest + XOR-permuted GLOBAL source chunks (m173). 256 thr.
__device__ __forceinline__ void stageA(const u16* base, int ldk, u16* lA, int t) {
  const int r = t >> 3, q = t & 7, wid = t >> 6;
  const int qs = (q ^ (r & 7)) << 3;                 // (r+32)&7 == r&7
  gl_lds16(base + (size_t)r * ldk + qs, lA + wid * 512);
  gl_lds16(base + (size_t)(r + 32) * ldk + qs, lA + 2048 + wid * 512);
}
// stage a 16 KB B tile (linear copy), 256 threads x 4 chunks of 16B.
__device__ __forceinline__ void stageB16(const u16* tile, u16* lB, int t) {
  const int wid = t >> 6;
#pragma unroll
  for (int i = 0; i < 4; ++i)
    gl_lds16(tile + ((size_t)i * 256 + t) * 8, lB + i * 2048 + wid * 512);
}

// ---------------------------------------------------------------------------
// pre: fused input-cast + weight prep (16 KB [hb][hh32][s] B tiles).
// B tile inner layout (u16): wn*4096 + (h*4+g)*512 + lane*8 + j
//   element = W_virtual[k = s*64 + h*32 + (lane>>4)*8 + j]
//                      [v = g*G + hb*64 + hh32*32 + wn*16 + (lane&15)]
// ---------------------------------------------------------------------------
__global__ __launch_bounds__(256) void hlstm_pre(
    const float* __restrict__ hhat0, const float* __restrict__ h0,
    const float* __restrict__ x, u16* __restrict__ abuf,
    const float* __restrict__ hweight, const float* __restrict__ hbias,
    const float* __restrict__ zw_h, const float* __restrict__ zw_x, const float* __restrict__ zw_b,
    const float* __restrict__ zb_h, const float* __restrict__ zb_x,
    const float* __restrict__ dw_h, const float* __restrict__ dw_x, const float* __restrict__ dw_b,
    const float* __restrict__ weight, const float* __restrict__ bias,
    u16* __restrict__ hw_fr, float* __restrict__ hbias_r,
    u16* __restrict__ w_fr,  float* __restrict__ bias_r,
    u16* __restrict__ whp_fr, u16* __restrict__ wxp_fr, u16* __restrict__ wbp_fr,
    float* __restrict__ bhp_r, float* __restrict__ bxp_r)
{
  if (blockIdx.x < 4096) {
    // ---- cast part: abuf[B][512] = bf16([hhat0 | h0 | x])
    const size_t stride = (size_t)4096 * 256;
    for (size_t i = (size_t)blockIdx.x * 256 + threadIdx.x;
         i < (size_t)BATCH * 64; i += stride) {
      const size_t b = i >> 6; const int c = (int)(i & 63);
      const float* src;
      if (c < 16)      src = hhat0 + b * 128 + c * 8;
      else if (c < 48) src = h0 + b * 256 + (size_t)(c - 16) * 8;
      else             src = x + b * 128 + (size_t)(c - 48) * 8;
      float4 v0 = ((const float4*)src)[0];
      float4 v1 = ((const float4*)src)[1];
      alignas(16) u16 o[8] = {f2b(v0.x), f2b(v0.y), f2b(v0.z), f2b(v0.w),
                              f2b(v1.x), f2b(v1.y), f2b(v1.z), f2b(v1.w)};
      *(uint4*)(abuf + i * 8) = *(const uint4*)o;
    }
    return;
  }
  const int tid = (blockIdx.x - 4096) * 256 + threadIdx.x;
  const int nt  = 512 * 256;

  // hw_fr: 32 tiles, tile = (hb*2+hh32)*8 + s  (hb<2, s<8)
  for (int i = tid; i < 32 * 8192; i += nt) {
    int tile = i >> 13, r = i & 8191;
    int wn = r >> 12, h = (r >> 11) & 1, g = (r >> 9) & 3;
    int lane = (r >> 3) & 63, j = r & 7;
    int hb = tile >> 4, hh32 = (tile >> 3) & 1, s = tile & 7;
    int k = s * 64 + h * 32 + (lane >> 4) * 8 + j;
    int col = g * 128 + hb * 64 + hh32 * 32 + wn * 16 + (lane & 15);
    hw_fr[i] = f2b(hweight[k * 512 + col]);
  }
  // w_fr: 48 tiles, tile = (hb*2+hh32)*6 + s  (hb<4, s<6)
  for (int i = tid; i < 48 * 8192; i += nt) {
    int tile = i >> 13, r = i & 8191;
    int wn = r >> 12, h = (r >> 11) & 1, g = (r >> 9) & 3;
    int lane = (r >> 3) & 63, j = r & 7;
    int hb = tile / 12, rem = tile % 12;
    int hh32 = rem / 6, s = rem % 6;
    int k = s * 64 + h * 32 + (lane >> 4) * 8 + j;
    int col = g * 256 + hb * 64 + hh32 * 32 + wn * 16 + (lane & 15);
    w_fr[i] = f2b(weight[k * 1024 + col]);
  }
  // folded hyper: 3 mats x 16 tiles, tile = (hb*2+hh32)*2 + s (hb<4, s<2)
  for (int i = tid; i < 3 * 16 * 8192; i += nt) {
    int mat = i / 131072, rem2 = i % 131072;
    int tile = rem2 >> 13, r = rem2 & 8191;
    int wn = r >> 12, h = (r >> 11) & 1, g = (r >> 9) & 3;
    int lane = (r >> 3) & 63, j = r & 7;
    int hb = tile >> 2, hh32 = (tile >> 1) & 1, s = tile & 1;
    int k = s * 64 + h * 32 + (lane >> 4) * 8 + j;       // 0..127
    int colh = hb * 64 + hh32 * 32 + wn * 16 + (lane & 15);
    const float* zw = (mat == 0) ? zw_h : (mat == 1) ? zw_x : zw_b;
    const float* dw = (mat == 0) ? dw_h : (mat == 1) ? dw_x : dw_b;
    float sv = 0.f;
#pragma unroll
    for (int e = 0; e < 16; ++e)
      sv += zw[k * 64 + g * 16 + e] * dw[g * 4096 + e * 256 + colh];
    u16* dst = (mat == 0) ? whp_fr : (mat == 1) ? wxp_fr : wbp_fr;
    dst[rem2] = f2b(sv);
  }
  // bias folds (virtual order hb*256 + g*64 + hh)
  for (int i = tid; i < 1024; i += nt) {
    int hb = i >> 8, g = (i >> 6) & 3, hh = i & 63;
    int h = hb * 64 + hh;
    float sh = 0.f, sx = 0.f;
#pragma unroll
    for (int e = 0; e < 16; ++e) {
      sh += zb_h[g * 16 + e] * dw_h[g * 4096 + e * 256 + h];
      sx += zb_x[g * 16 + e] * dw_x[g * 4096 + e * 256 + h];
    }
    bhp_r[i] = sh; bxp_r[i] = sx;
    bias_r[i] = bias[g * 256 + h];
  }
  for (int i = tid; i < 512; i += nt) {
    int gate = (i >> 6) & 3, hb = i >> 8, hh = i & 63;
    hbias_r[i] = hbias[gate * 128 + hb * 64 + hh];
  }
}

// ---------------------------------------------------------------------------
// k1: hyper GEMM (K=512, 8 steps) + hyper LSTM. 2048 blocks x 256 threads.
// 128x128 tile, A+B via LDS double-buffer, 2-phase ledger.
// ---------------------------------------------------------------------------
__global__ __launch_bounds__(256, 2) void hlstm_k1(
    const u16* __restrict__ abuf, const float* __restrict__ chat0,
    const u16* __restrict__ hw_fr, const float* __restrict__ hbias_r,
    float* __restrict__ d_out, u16* __restrict__ hbuf)
{
  __shared__ alignas(16) u16 lA[2][8192];   // 2 x 16 KB (128 rows x 64 k, swz)
  __shared__ alignas(16) u16 lB[2][8192];   // 2 x 16 KB B tiles
  const int f = blockIdx.x;                 // 0..2047
  const int xcd = f & 7, u = f >> 3;        // u: 0..255
  const int rb = xcd * 64 + (u >> 2);       // 128-row group
  const int sub = u & 3, hb = sub >> 1, hh32 = sub & 1;
  const int t = threadIdx.x;
  const int lane = t & 63, w = t >> 6;
  const int wm = w >> 1, wn = w & 1;
  const int lr = lane & 15, kg = lane >> 4;

  f32x4 acc[4][4];
  const f32x4 zzero = {0.f, 0.f, 0.f, 0.f};
#pragma unroll
  for (int mf = 0; mf < 4; ++mf)
#pragma unroll
    for (int g = 0; g < 4; ++g) acc[mf][g] = zzero;

  const u16* arow = abuf + (size_t)rb * 128 * 512;
  auto btile = [&](int s) -> const u16* {
    return hw_fr + (size_t)((hb * 2 + hh32) * 8 + s) * 8192;
  };
  auto stage = [&](int s, int buf) {
    stageA(arow + s * 64, 512, lA[buf], t);
    stageA(arow + s * 64 + (size_t)64 * 512, 512, lA[buf] + 4096, t);
    stageB16(btile(s), lB[buf], t);
  };
  auto sweep = [&](const u16* cA, const u16* cB) {
#pragma unroll
    for (int h = 0; h < 2; ++h) {
      bf16x8 bfr[4];
#pragma unroll
      for (int g = 0; g < 4; ++g)
        bfr[g] = *(const bf16x8*)&cB[wn * 4096 + (h * 4 + g) * 512 + lane * 8];
#pragma unroll
      for (int mf = 0; mf < 4; ++mf) {
        bf16x8 afr = *(const bf16x8*)&cA[swz(wm * 64 + mf * 16 + lr, h * 32 + kg * 8)];
#pragma unroll
        for (int g = 0; g < 4; ++g)
          acc[mf][g] = __builtin_amdgcn_mfma_f32_16x16x32_bf16(afr, bfr[g], acc[mf][g], 0, 0, 0);
      }
    }
  };

  stage(0, 0);
  wait0_bar();
#pragma unroll
  for (int ks = 0; ks < 8; ++ks) {
    const int cur = ks & 1;
    if (ks < 7) stage(ks + 1, cur ^ 1);
    sweep(lA[cur], lB[cur]);
    if (ks < 7) wait0_bar();
  }

  float hb4[4];
#pragma unroll
  for (int g = 0; g < 4; ++g)
    hb4[g] = hbias_r[hb * 256 + g * 64 + hh32 * 32 + wn * 16 + lr];
  const int zc = hb * 64 + hh32 * 32 + wn * 16 + lr;
  float* out_hh = d_out + (size_t)BATCH * 512;
  float* out_ch = d_out + (size_t)BATCH * 640;
#pragma unroll
  for (int mf = 0; mf < 4; ++mf)
#pragma unroll
    for (int r = 0; r < 4; ++r) {
      const int row = rb * 128 + wm * 64 + mf * 16 + kg * 4 + r;
      const float gi = acc[mf][0][r] + hb4[0];
      const float gg = acc[mf][1][r] + hb4[1];
      const float gf = acc[mf][2][r] + hb4[2];
      const float go = acc[mf][3][r] + hb4[3];
      const float c0v = chat0[(size_t)row * 128 + zc];
      const float c1v = sigf(gf) * c0v + sigf(gi) * tanhfast(gg);
      const float h1v = sigf(go) * tanhfast(c1v);
      out_hh[(size_t)row * 128 + zc] = h1v;
      out_ch[(size_t)row * 128 + zc] = c1v;
      hbuf[(size_t)row * 128 + zc] = f2b(h1v);
    }
}

// ---------------------------------------------------------------------------
// k2: hyper-first 12 K-steps (s0-1 d_yh -> dsc ; s2-3 d_yx -> dsc ; s4-9 main
// gpre ; s9 acc*=dsc ; s10-11 d_yb MFMA C-in). 4096 blocks x 256 threads.
// 128x128 tile, A+B via LDS double-buffer, 2-phase ledger.
// ---------------------------------------------------------------------------
__global__ __launch_bounds__(256, 2) void hlstm_k2(
    const u16* __restrict__ abuf, const u16* __restrict__ hbuf,
    const float* __restrict__ c0,
    const u16* __restrict__ w_fr, const float* __restrict__ bias_r,
    const u16* __restrict__ whp_fr, const u16* __restrict__ wxp_fr, const u16* __restrict__ wbp_fr,
    const float* __restrict__ bhp_r, const float* __restrict__ bxp_r,
    float* __restrict__ d_out)
{
  __shared__ alignas(16) u16 lA[2][8192];
  __shared__ alignas(16) u16 lB[2][8192];
  const int f = blockIdx.x;                 // 0..4095
  const int xcd = f & 7, u = f >> 3;        // u: 0..511
  const int rb = xcd * 64 + (u >> 3);       // 128-row group
  const int sub = u & 7, hb = sub >> 1, hh32 = sub & 1;
  const int t = threadIdx.x;
  const int lane = t & 63, w = t >> 6;
  const int wm = w >> 1, wn = w & 1;
  const int lr = lane & 15, kg = lane >> 4;

  const u16* amain = abuf + (size_t)rb * 128 * 512 + 128;   // [h0|x] cols, ld 512
  const u16* ahyp  = hbuf + (size_t)rb * 128 * 128;         // ld 128

  // steps: 0..3 hyper (Wh',Wx'), 4..9 main, 10..11 hyper (Wb')
  auto aptr = [&](int s) -> const u16* {
    if (s >= 4 && s < 10) return amain + (s - 4) * 64;
    return ahyp + (s & 1) * 64;
  };
  auto aldk = [&](int s) -> int { return (s >= 4 && s < 10) ? 512 : 128; };
  auto bptr = [&](int s) -> const u16* {
    const int base = (hb * 2 + hh32);
    if (s < 2)  return whp_fr + (size_t)(base * 2 + s) * 8192;
    if (s < 4)  return wxp_fr + (size_t)(base * 2 + s - 2) * 8192;
    if (s < 10) return w_fr  + (size_t)(base * 6 + s - 4) * 8192;
    return wbp_fr + (size_t)(base * 2 + s - 10) * 8192;
  };

  f32x4 acc[4][4];
  const f32x4 zzero = {0.f, 0.f, 0.f, 0.f};
#pragma unroll
  for (int mf = 0; mf < 4; ++mf)
#pragma unroll
    for (int g = 0; g < 4; ++g) acc[mf][g] = zzero;

  unsigned dsc[4][4][2];                    // packed-bf16 running dscale (32 VGPR)

  auto stage = [&](int s, int buf) {
    const u16* ap = aptr(s); const int ldk = aldk(s);
    stageA(ap, ldk, lA[buf], t);
    stageA(ap + (size_t)64 * ldk, ldk, lA[buf] + 4096, t);
    stageB16(bptr(s), lB[buf], t);
  };
  auto sweep = [&](const u16* cA, const u16* cB) {
#pragma unroll
    for (int h = 0; h < 2; ++h) {
      bf16x8 bfr[4];
#pragma unroll
      for (int g = 0; g < 4; ++g)
        bfr[g] = *(const bf16x8*)&cB[wn * 4096 + (h * 4 + g) * 512 + lane * 8];
#pragma unroll
      for (int mf = 0; mf < 4; ++mf) {
        bf16x8 afr = *(const bf16x8*)&cA[swz(wm * 64 + mf * 16 + lr, h * 32 + kg * 8)];
#pragma unroll
        for (int g = 0; g < 4; ++g)
          acc[mf][g] = __builtin_amdgcn_mfma_f32_16x16x32_bf16(afr, bfr[g], acc[mf][g], 0, 0, 0);
      }
    }
  };

  stage(0, 0);
  wait0_bar();
#pragma unroll
  for (int s = 0; s < 12; ++s) {
    const int cur = s & 1;
    if (s < 11) stage(s + 1, cur ^ 1);
    if (s == 2 || s == 4) {                 // new phase: re-zero single acc
#pragma unroll
      for (int mf = 0; mf < 4; ++mf)
#pragma unroll
        for (int g = 0; g < 4; ++g) acc[mf][g] = zzero;
    }
    sweep(lA[cur], lB[cur]);

    if (s == 1) {                           // dsc = pack(d_yh + bh')
      float bh4[4];
#pragma unroll
      for (int g = 0; g < 4; ++g)
        bh4[g] = bhp_r[hb * 256 + g * 64 + hh32 * 32 + wn * 16 + lr];
#pragma unroll
      for (int mf = 0; mf < 4; ++mf)
#pragma unroll
        for (int g = 0; g < 4; ++g) {
          dsc[mf][g][0] = pk2(acc[mf][g][0] + bh4[g], acc[mf][g][1] + bh4[g]);
          dsc[mf][g][1] = pk2(acc[mf][g][2] + bh4[g], acc[mf][g][3] + bh4[g]);
        }
    } else if (s == 3) {                    // dsc *= (d_yx + bx')
      float bx4[4];
#pragma unroll
      for (int g = 0; g < 4; ++g)
        bx4[g] = bxp_r[hb * 256 + g * 64 + hh32 * 32 + wn * 16 + lr];
#pragma unroll
      for (int mf = 0; mf < 4; ++mf)
#pragma unroll
        for (int g = 0; g < 4; ++g) {
          float d0 = upk_lo(dsc[mf][g][0]) * (acc[mf][g][0] + bx4[g]);
          float d1 = upk_hi(dsc[mf][g][0]) * (acc[mf][g][1] + bx4[g]);
          float d2 = upk_lo(dsc[mf][g][1]) * (acc[mf][g][2] + bx4[g]);
          float d3 = upk_hi(dsc[mf][g][1]) * (acc[mf][g][3] + bx4[g]);
          dsc[mf][g][0] = pk2(d0, d1);
          dsc[mf][g][1] = pk2(d2, d3);
        }
    } else if (s == 9) {                    // acc(gpre) *= dscale
#pragma unroll
      for (int mf = 0; mf < 4; ++mf)
#pragma unroll
        for (int g = 0; g < 4; ++g) {
          acc[mf][g][0] *= upk_lo(dsc[mf][g][0]);
          acc[mf][g][1] *= upk_hi(dsc[mf][g][0]);
          acc[mf][g][2] *= upk_lo(dsc[mf][g][1]);
          acc[mf][g][3] *= upk_hi(dsc[mf][g][1]);
        }
    }
    if (s < 11) wait0_bar();
  }

  // ---- epilogue: main LSTM cell (acc = gpre*dscale + d_yb)
  const int hcol = hb * 64 + hh32 * 32 + wn * 16 + lr;
  float b4[4];
#pragma unroll
  for (int g = 0; g < 4; ++g)
    b4[g] = bias_r[hb * 256 + g * 64 + hh32 * 32 + wn * 16 + lr];
  float* out_c1 = d_out + (size_t)BATCH * 256;
#pragma unroll
  for (int mf = 0; mf < 4; ++mf)
#pragma unroll
    for (int r = 0; r < 4; ++r) {
      const int row = rb * 128 + wm * 64 + mf * 16 + kg * 4 + r;
      const float gi = acc[mf][0][r] + b4[0];
      const float gg = acc[mf][1][r] + b4[1];
      const float gf = acc[mf][2][r] + b4[2];
      const float go = acc[mf][3][r] + b4[3];
      const float c0v = c0[(size_t)row * 256 + hcol];
      const float c1v = sigf(gf) * c0v + sigf(gi) * tanhfast(gg);
      const float h1v = sigf(go) * tanhfast(c1v);
      d_out[(size_t)row * 256 + hcol]  = h1v;
      out_c1[(size_t)row * 256 + hcol] = c1v;
    }
}

// ---------------------------------------------------------------------------
extern "C" void kernel_launch(void* const* d_in, const int* in_sizes, int n_in,
                              void* d_out, int out_size, void* d_ws, size_t ws_size,
                              hipStream_t stream)
{
  (void)in_sizes; (void)n_in; (void)out_size; (void)ws_size;
  const float* x       = (const float*)d_in[0];
  const float* h0      = (const float*)d_in[1];
  const float* c0      = (const float*)d_in[2];
  const float* hhat0   = (const float*)d_in[3];
  const float* chat0   = (const float*)d_in[4];
  const float* hweight = (const float*)d_in[5];
  const float* hbias   = (const float*)d_in[6];
  const float* zw_h    = (const float*)d_in[7];
  const float* zw_x    = (const float*)d_in[8];
  const float* zw_b    = (const float*)d_in[9];
  const float* zb_h    = (const float*)d_in[10];
  const float* zb_x    = (const float*)d_in[11];
  const float* dw_h    = (const float*)d_in[12];
  const float* dw_x    = (const float*)d_in[13];
  const float* dw_b    = (const float*)d_in[14];
  const float* weight  = (const float*)d_in[15];
  const float* bias    = (const float*)d_in[16];

  // workspace layout (bytes, 16B-aligned); total ~86 MB
  char* wsb = (char*)d_ws;
  u16*   abuf    = (u16*)(wsb + 0);              // B*512*2   = 67108864
  u16*   hbuf    = (u16*)(wsb + 67108864);       // B*128*2   = 16777216
  u16*   hw_fr   = (u16*)(wsb + 83886080);       // 32*8192*2  = 524288
  u16*   w_fr    = (u16*)(wsb + 84410368);       // 48*8192*2  = 786432
  u16*   whp_fr  = (u16*)(wsb + 85196800);       // 16*8192*2  = 262144
  u16*   wxp_fr  = (u16*)(wsb + 85458944);
  u16*   wbp_fr  = (u16*)(wsb + 85721088);
  float* hbias_r = (float*)(wsb + 85983232);     // 512*4
  float* bias_r  = (float*)(wsb + 85985280);     // 1024*4
  float* bhp_r   = (float*)(wsb + 85989376);     // 1024*4
  float* bxp_r   = (float*)(wsb + 85993472);     // 1024*4

  hlstm_pre<<<dim3(4608), dim3(256), 0, stream>>>(
      hhat0, h0, x, abuf,
      hweight, hbias, zw_h, zw_x, zw_b, zb_h, zb_x, dw_h, dw_x, dw_b, weight, bias,
      hw_fr, hbias_r, w_fr, bias_r, whp_fr, wxp_fr, wbp_fr, bhp_r, bxp_r);

  hlstm_k1<<<dim3(2048), dim3(256), 0, stream>>>(
      abuf, chat0, hw_fr, hbias_r, (float*)d_out, hbuf);

  hlstm_k2<<<dim3(4096), dim3(256), 0, stream>>>(
      abuf, hbuf, c0, w_fr, bias_r, whp_fr, wxp_fr, wbp_fr, bhp_r, bxp_r, (float*)d_out);
}